// Round 17
// baseline (269.310 us; speedup 1.0000x reference)
//
#include <hip/hip_runtime.h>

// ---------------------------------------------------------------------------
// MultiHeadAttention: out = softmax_causal((XWq^T)(XWk^T)^T / sqrt(S)) (XWv^T) Wo^T + b
// B=2, S=2048, D=2048, H=16, HD=128.  All compute in bf16 MFMA, fp32 accum.
// Softmax in exp2 domain (Wq pre-scaled by (1/sqrt(S))*log2(e)).
// qk: 256x256 8-phase core; vt/o: 128x256 4-phase core; all XCD-chunked (T1).
// attn: 4-wave blocks owning 64 q-rows, KVBLK=32, 36KB LDS -> 4 blocks/CU
// co-resident with a 1024-block LPT grid (real backfill supply); lazy-max
// softmax; swizzled P path; setprio (T5).
// ---------------------------------------------------------------------------

typedef __attribute__((ext_vector_type(8))) short short8;
typedef __attribute__((ext_vector_type(4))) float f32x4;

#define SEQ 2048
#define DM  2048
#define NHD 128
#define NT  32    // K-tiles of 64 (GEMM)
#define QSCALE (0.022097086912079608f * 1.4426950408889634f)  // 1/sqrt(2048) * log2(e)

#define EXP2F(x) __builtin_amdgcn_exp2f(x)
#define WAITV(N) asm volatile("s_waitcnt vmcnt(" #N ")" ::: "memory")

__device__ __forceinline__ unsigned short f2bf(float f) {   // RNE
  unsigned u = __builtin_bit_cast(unsigned, f);
  u += 0x7FFFu + ((u >> 16) & 1u);
  return (unsigned short)(u >> 16);
}
__device__ __forceinline__ unsigned short f2bf_fast(float f) {  // round-half-up
  unsigned u = __builtin_bit_cast(unsigned, f);
  return (unsigned short)((u + 0x8000u) >> 16);
}

__device__ __forceinline__ void gll16(const void* g, void* l) {
  __builtin_amdgcn_global_load_lds((const __attribute__((address_space(1))) void*)g,
                                   (__attribute__((address_space(3))) void*)l, 16, 0, 0);
}

// ---- DPP 16-lane reductions (VALU pipe, no LDS crossbar) ------------------
template <int CTRL>
__device__ __forceinline__ float dpp_mv(float x) {
  int xi = __builtin_bit_cast(int, x);
  return __builtin_bit_cast(float,
      __builtin_amdgcn_update_dpp(xi, xi, CTRL, 0xF, 0xF, false));
}
__device__ __forceinline__ float red16_max(float x) {
  x = fmaxf(x, dpp_mv<0xB1>(x));
  x = fmaxf(x, dpp_mv<0x4E>(x));
  x = fmaxf(x, dpp_mv<0x124>(x));
  x = fmaxf(x, dpp_mv<0x128>(x));
  return x;
}
__device__ __forceinline__ float red16_sum(float x) {
  x += dpp_mv<0xB1>(x);
  x += dpp_mv<0x4E>(x);
  x += dpp_mv<0x124>(x);
  x += dpp_mv<0x128>(x);
  return x;
}

// ---------------- fused cast: X + 4 weights in one launch ------------------
__global__ __launch_bounds__(256) void cast_all_k(const float* __restrict__ X,
                                                  const float* __restrict__ Wq,
                                                  const float* __restrict__ Wk,
                                                  const float* __restrict__ Wv,
                                                  const float* __restrict__ Wo,
                                                  unsigned short* __restrict__ Xb,
                                                  unsigned short* __restrict__ Wqb,
                                                  unsigned short* __restrict__ Wkb,
                                                  unsigned short* __restrict__ Wvb,
                                                  unsigned short* __restrict__ Wob) {
  int i = blockIdx.x * 256 + threadIdx.x;
  const float* src;
  unsigned short* dst;
  int j;
  float sc = 1.0f;
  if (i < 1048576) {
    src = X; dst = Xb; j = i;
  } else {
    int k = i - 1048576;
    int r = k >> 19; j = k & 524287;
    src = (r == 0) ? Wq : (r == 1) ? Wk : (r == 2) ? Wv : Wo;
    dst = (r == 0) ? Wqb : (r == 1) ? Wkb : (r == 2) ? Wvb : Wob;
    if (r == 0) sc = QSCALE;
  }
  const f32x4* p = (const f32x4*)src + (size_t)j * 2;
  f32x4 a = p[0], b = p[1];
  short8 o;
  o[0] = (short)f2bf(a[0] * sc); o[1] = (short)f2bf(a[1] * sc);
  o[2] = (short)f2bf(a[2] * sc); o[3] = (short)f2bf(a[3] * sc);
  o[4] = (short)f2bf(b[0] * sc); o[5] = (short)f2bf(b[1] * sc);
  o[6] = (short)f2bf(b[2] * sc); o[7] = (short)f2bf(b[3] * sc);
  *(short8*)(dst + (size_t)j * 8) = o;
}

// ---------------- shared staging helper (GEMM) -----------------------------
__device__ __forceinline__ void stage_half(const unsigned short* __restrict__ gbase,
                                           unsigned short* lhalf, int tid) {
#pragma unroll
  for (int c = 0; c < 2; ++c) {
    int G = c * 512 + tid;
    int row = G >> 3, g = G & 7;
    int gs = g ^ (row & 7);
    gll16(gbase + (size_t)row * DM + gs * 8, lhalf + (size_t)G * 8);
  }
}

// ---------------- 256x256 8-phase core (qk) --------------------------------
#define LOADAF(MH)                                                              \
  _Pragma("unroll") for (int mi = 0; mi < 4; ++mi)                              \
    _Pragma("unroll") for (int ks = 0; ks < 2; ++ks) {                          \
      int row = wm * 64 + mi * 16 + lr;                                         \
      af[mi][ks] = *(const short8*)&lA[(MH) * 8192 + row * 64 +                 \
                                       (((ks * 4 + kb) ^ (row & 7)) * 8)];      \
    }

#define PHASE(MH, NH, STG, WV)                                                  \
  {                                                                             \
    const unsigned short* lBh = lB + (NH) * 8192;                               \
    short8 bfr[2][2];                                                           \
    _Pragma("unroll") for (int ni = 0; ni < 2; ++ni)                            \
      _Pragma("unroll") for (int ks = 0; ks < 2; ++ks) {                        \
        int row = wn * 32 + ni * 16 + lr;                                       \
        bfr[ni][ks] = *(const short8*)&lBh[row * 64 + (((ks * 4 + kb) ^ (row & 7)) * 8)]; \
      }                                                                         \
    STG;                                                                        \
    __builtin_amdgcn_s_barrier();                                               \
    __builtin_amdgcn_s_setprio(1);                                              \
    _Pragma("unroll") for (int mi = 0; mi < 4; ++mi)                            \
      _Pragma("unroll") for (int ni = 0; ni < 2; ++ni) {                        \
        acc[MH][NH][mi][ni] = __builtin_amdgcn_mfma_f32_16x16x32_bf16(          \
            af[mi][0], bfr[ni][0], acc[MH][NH][mi][ni], 0, 0, 0);               \
        acc[MH][NH][mi][ni] = __builtin_amdgcn_mfma_f32_16x16x32_bf16(          \
            af[mi][1], bfr[ni][1], acc[MH][NH][mi][ni], 0, 0, 0);               \
      }                                                                         \
    __builtin_amdgcn_s_setprio(0);                                              \
    WV;                                                                         \
    __builtin_amdgcn_s_barrier();                                               \
  }

__device__ __forceinline__ void gemm256_core(const unsigned short* __restrict__ A,
                                             const unsigned short* __restrict__ B,
                                             unsigned short* LA, unsigned short* LB,
                                             f32x4 acc[2][2][4][2], int m0, int n0) {
  const int tid = threadIdx.x;
  const int w = tid >> 6, l = tid & 63;
  const int lr = l & 15, kb = l >> 4;
  const int wm = w >> 2, wn = w & 3;

  stage_half(A + (size_t)m0 * DM, LA, tid);
  stage_half(B + (size_t)n0 * DM, LB, tid);
  stage_half(B + (size_t)n0 * DM + (size_t)128 * DM, LB + 8192, tid);
  stage_half(A + (size_t)m0 * DM + (size_t)128 * DM, LA + 8192, tid);
  WAITV(4);
  __builtin_amdgcn_s_barrier();

#pragma unroll 1
  for (int t = 0; t < NT; ++t) {
    const unsigned short* lA = LA + (t & 1) * 16384;
    const unsigned short* lB = LB + (t & 1) * 16384;
    unsigned short* sA = LA + ((t + 1) & 1) * 16384;
    unsigned short* sB = LB + ((t + 1) & 1) * 16384;
    const unsigned short* gA = A + (size_t)m0 * DM + (t + 1) * 64;
    const unsigned short* gB = B + (size_t)n0 * DM + (t + 1) * 64;
    const bool st = (t + 1 < NT);
    short8 af[4][2];
    LOADAF(0);
    PHASE(0, 0, if (st) stage_half(gA, sA, tid),
                if (st) { WAITV(4); } else { WAITV(2); });
    PHASE(0, 1, if (st) stage_half(gB, sB, tid),
                if (st) { WAITV(4); } else { WAITV(0); });
    LOADAF(1);
    PHASE(1, 0, if (st) stage_half(gB + (size_t)128 * DM, sB + 8192, tid), );
    PHASE(1, 1, if (st) stage_half(gA + (size_t)128 * DM, sA + 8192, tid),
                if (st) { WAITV(4); });
  }
}

// Q and K projections. Grid (8,16,2). XCD-chunk remap: per XCD 4y x 4x x 2z.
__global__ __launch_bounds__(512, 2) void gemm_qk_k(const unsigned short* __restrict__ X,
                                                    const unsigned short* __restrict__ Wq,
                                                    const unsigned short* __restrict__ Wk,
                                                    unsigned short* __restrict__ Qo,
                                                    unsigned short* __restrict__ Ko) {
  __shared__ unsigned short LA[32768];
  __shared__ unsigned short LB[32768];
  const int lin = blockIdx.x + 8 * (blockIdx.y + 16 * blockIdx.z);
  const int c = lin & 7, idx = lin >> 3;
  const int xb = (c & 1) * 4 + ((idx >> 2) & 3);
  const int yb = (c >> 1) * 4 + (idx & 3);
  const int zb = idx >> 4;
  const unsigned short* W = zb ? Wk : Wq;
  unsigned short* Y = zb ? Ko : Qo;
  const int m0 = yb * 256, n0 = xb * 256;
  const int tid = threadIdx.x, w = tid >> 6, l = tid & 63;
  const int lr = l & 15, kb = l >> 4;
  const int wm = w >> 2, wn = w & 3;
  f32x4 acc[2][2][4][2] = {};
  gemm256_core(X, W, LA, LB, acc, m0, n0);
#pragma unroll
  for (int mh = 0; mh < 2; ++mh)
#pragma unroll
    for (int nh = 0; nh < 2; ++nh)
#pragma unroll
      for (int mi = 0; mi < 4; ++mi)
#pragma unroll
        for (int ni = 0; ni < 2; ++ni)
#pragma unroll
          for (int rr = 0; rr < 4; ++rr) {
            int row = m0 + mh * 128 + wm * 64 + mi * 16 + kb * 4 + rr;
            int col = n0 + nh * 128 + wn * 32 + ni * 16 + lr;
            Y[(size_t)row * DM + col] = f2bf(acc[mh][nh][mi][ni][rr]);
          }
}

// ---------------- 128x256 4-phase core (vt, o) -----------------------------
#define PH2(NH, STG, WV)                                                        \
  {                                                                             \
    const unsigned short* lBh = lB + (NH) * 8192;                               \
    short8 bfr[2][2];                                                           \
    _Pragma("unroll") for (int ni = 0; ni < 2; ++ni)                            \
      _Pragma("unroll") for (int ks = 0; ks < 2; ++ks) {                        \
        int row = wn * 32 + ni * 16 + lr;                                       \
        bfr[ni][ks] = *(const short8*)&lBh[row * 64 + (((ks * 4 + kb) ^ (row & 7)) * 8)]; \
      }                                                                         \
    STG;                                                                        \
    __builtin_amdgcn_s_barrier();                                               \
    __builtin_amdgcn_s_setprio(1);                                              \
    _Pragma("unroll") for (int mi = 0; mi < 4; ++mi)                            \
      _Pragma("unroll") for (int ni = 0; ni < 2; ++ni) {                        \
        acc[NH][mi][ni] = __builtin_amdgcn_mfma_f32_16x16x32_bf16(              \
            af[mi][0], bfr[ni][0], acc[NH][mi][ni], 0, 0, 0);                   \
        acc[NH][mi][ni] = __builtin_amdgcn_mfma_f32_16x16x32_bf16(              \
            af[mi][1], bfr[ni][1], acc[NH][mi][ni], 0, 0, 0);                   \
      }                                                                         \
    __builtin_amdgcn_s_setprio(0);                                              \
    WV;                                                                         \
    __builtin_amdgcn_s_barrier();                                               \
  }

__device__ __forceinline__ void gemm128x256_core(const unsigned short* __restrict__ A,
                                                 const unsigned short* __restrict__ B,
                                                 unsigned short* LA, unsigned short* LB,
                                                 f32x4 acc[2][4][2], int m0, int n0) {
  const int tid = threadIdx.x;
  const int w = tid >> 6, l = tid & 63;
  const int lr = l & 15, kb = l >> 4;
  const int wm = w >> 2, wn = w & 3;

  stage_half(A + (size_t)m0 * DM, LA, tid);
  stage_half(B + (size_t)n0 * DM, LB, tid);
  stage_half(B + (size_t)n0 * DM + (size_t)128 * DM, LB + 8192, tid);
  WAITV(2);
  __builtin_amdgcn_s_barrier();

#pragma unroll 1
  for (int t = 0; t < NT; ++t) {
    const unsigned short* lA = LA + (t & 1) * 8192;
    const unsigned short* lB = LB + (t & 1) * 16384;
    unsigned short* sA = LA + ((t + 1) & 1) * 8192;
    unsigned short* sB = LB + ((t + 1) & 1) * 16384;
    const unsigned short* gA = A + (size_t)m0 * DM + (t + 1) * 64;
    const unsigned short* gB = B + (size_t)n0 * DM + (t + 1) * 64;
    const bool st = (t + 1 < NT);
    short8 af[4][2];
#pragma unroll
    for (int mi = 0; mi < 4; ++mi)
#pragma unroll
      for (int ks = 0; ks < 2; ++ks) {
        int row = wm * 64 + mi * 16 + lr;
        af[mi][ks] = *(const short8*)&lA[row * 64 + (((ks * 4 + kb) ^ (row & 7)) * 8)];
      }
    PH2(0, if (st) stage_half(gA, sA, tid),
           if (st) { WAITV(2); } else { WAITV(0); });
    PH2(1, if (st) { stage_half(gB, sB, tid); stage_half(gB + (size_t)128 * DM, sB + 8192, tid); },
           if (st) { WAITV(2); });
  }
}

__global__ __launch_bounds__(512, 2) void gemm_vt_k(const unsigned short* __restrict__ Wv,
                                                    const unsigned short* __restrict__ X,
                                                    unsigned short* __restrict__ Vt) {
  __shared__ unsigned short LA[16384];
  __shared__ unsigned short LB[32768];
  const int lin = blockIdx.x + 16 * blockIdx.y;
  const int c = lin & 7, idx = lin >> 3;
  const int yb = (c >> 2) * 8 + (idx & 7);
  const int xb = (c & 3) * 4 + (idx >> 3);
  const int m0 = yb * 128, n0 = xb * 256;
  const int tid = threadIdx.x, w = tid >> 6, l = tid & 63;
  const int lr = l & 15, kb = l >> 4;
  const int wm = w >> 2, wn = w & 3;
  f32x4 acc[2][4][2] = {};
  gemm128x256_core(Wv, X, LA, LB, acc, m0, n0);
#pragma unroll
  for (int nh = 0; nh < 2; ++nh)
#pragma unroll
    for (int mi = 0; mi < 4; ++mi)
#pragma unroll
      for (int ni = 0; ni < 2; ++ni)
#pragma unroll
        for (int rr = 0; rr < 4; ++rr) {
          int i = m0 + wm * 64 + mi * 16 + kb * 4 + rr;             // h*128+d
          int j = n0 + nh * 128 + wn * 32 + ni * 16 + lr;           // b*2048+s
          Vt[((size_t)(j >> 11) * 2048 + i) * 2048 + (j & 2047)] = f2bf(acc[nh][mi][ni][rr]);
        }
}

__global__ __launch_bounds__(512, 2) void gemm_o_k(const unsigned short* __restrict__ A,
                                                   const unsigned short* __restrict__ W,
                                                   const float* __restrict__ bias,
                                                   float* __restrict__ Y) {
  __shared__ unsigned short LA[16384];
  __shared__ unsigned short LB[32768];
  const int lin = blockIdx.x + 8 * blockIdx.y;
  const int c = lin & 7, idx = lin >> 3;
  const int yb = (c >> 1) * 8 + (idx & 7);
  const int xb = (c & 1) * 4 + (idx >> 3);
  const int m0 = yb * 128, n0 = xb * 256;
  const int tid = threadIdx.x, w = tid >> 6, l = tid & 63;
  const int lr = l & 15, kb = l >> 4;
  const int wm = w >> 2, wn = w & 3;
  f32x4 acc[2][4][2] = {};
  gemm128x256_core(A, W, LA, LB, acc, m0, n0);
#pragma unroll
  for (int nh = 0; nh < 2; ++nh)
#pragma unroll
    for (int mi = 0; mi < 4; ++mi)
#pragma unroll
      for (int ni = 0; ni < 2; ++ni)
#pragma unroll
        for (int rr = 0; rr < 4; ++rr) {
          int row = m0 + wm * 64 + mi * 16 + kb * 4 + rr;
          int col = n0 + nh * 128 + wn * 32 + ni * 16 + lr;
          Y[(size_t)row * DM + col] = acc[nh][mi][ni][rr] + bias[col];
        }
}

// ---------------- flash attention, causal, exp2-domain softmax -------------
// 256-thread staging of one 32-key tile: K 512 granules + V 512 granules.
__device__ __forceinline__ void stage_tiles4(const unsigned short* __restrict__ Kh,
                                             const unsigned short* __restrict__ Vh,
                                             unsigned short* KL, unsigned short* VL,
                                             int kv0, int t) {
#pragma unroll
  for (int c = 0; c < 2; ++c) {          // K: slot S = row*16 + (g^(row&7))
    int S = c * 256 + t;
    int row = S >> 4, g = (S & 15) ^ (row & 7);
    gll16(Kh + (size_t)(kv0 + row) * DM + g * 8, KL + (size_t)S * 8);
  }
#pragma unroll
  for (int c = 0; c < 2; ++c) {          // V: slot S = d*4 + (g^(d&3))
    int S = c * 256 + t;
    int d = S >> 2, g = (S & 3) ^ (d & 3);
    gll16(Vh + (size_t)d * SEQ + kv0 + g * 8, VL + (size_t)S * 8);
  }
}

// One 32-key tile for one 16-row q-group. Lazy-max softmax; P [16q][32key]
// per wave (write g = (key>>3)^(prow&3), read kb^(lr&3) involution).
__device__ __forceinline__ void attn_tile32(const unsigned short* __restrict__ Kc,
                                            const unsigned short* __restrict__ Vc,
                                            unsigned short* __restrict__ Pw,
                                            const short8 qf[4], f32x4 ctx[8],
                                            float mrow[4], float lpart[4],
                                            int qw, int kv0, int lr, int kb) {
  f32x4 s[2];
  __builtin_amdgcn_s_setprio(1);
#pragma unroll
  for (int ct = 0; ct < 2; ++ct) {
    s[ct] = (f32x4){0.f, 0.f, 0.f, 0.f};
    int krow = ct * 16 + lr;
#pragma unroll
    for (int ks = 0; ks < 4; ++ks) {
      short8 bf = *(const short8*)&Kc[krow * 128 + (((ks * 4 + kb) ^ (krow & 7)) * 8)];
      s[ct] = __builtin_amdgcn_mfma_f32_16x16x32_bf16(qf[ks], bf, s[ct], 0, 0, 0);
    }
  }
  __builtin_amdgcn_s_setprio(0);
  if (kv0 + 31 > qw) {                  // diagonal tile: causal mask
#pragma unroll
    for (int r = 0; r < 4; ++r) {
      const int qi = qw + kb * 4 + r;
#pragma unroll
      for (int ct = 0; ct < 2; ++ct)
        if (kv0 + ct * 16 + lr > qi) s[ct][r] = -3.0e4f;
    }
  }
  float mxl[4];
#pragma unroll
  for (int r = 0; r < 4; ++r)
    mxl[r] = fmaxf(s[0][r], s[1][r]);
  bool hit = (mxl[0] > mrow[0] + 8.f) | (mxl[1] > mrow[1] + 8.f) |
             (mxl[2] > mrow[2] + 8.f) | (mxl[3] > mrow[3] + 8.f);
  if (__any(hit)) {                     // rare after first tile
#pragma unroll
    for (int r = 0; r < 4; ++r) {
      float mx = red16_max(mxl[r]);
      if (mx > mrow[r] + 8.f) {
        float alpha = EXP2F(mrow[r] - mx);
        mrow[r] = mx;
        lpart[r] *= alpha;
#pragma unroll
        for (int cc = 0; cc < 8; ++cc) ctx[cc][r] *= alpha;
      }
    }
  }
  float pe[2][4];
#pragma unroll
  for (int r = 0; r < 4; ++r) {
#pragma unroll
    for (int ct = 0; ct < 2; ++ct) {
      float e = EXP2F(s[ct][r] - mrow[r]);
      pe[ct][r] = e;
      lpart[r] += e;
    }
  }
  // P write: key = ct*16+lr -> granule gk = ct*2+(lr>>3), swizzled ^(prow&3)
#pragma unroll
  for (int ct = 0; ct < 2; ++ct)
#pragma unroll
    for (int r = 0; r < 4; ++r) {
      int prow = kb * 4 + r;
      int gk = ct * 2 + (lr >> 3);
      Pw[prow * 32 + ((gk ^ (prow & 3)) * 8) + (lr & 7)] = f2bf_fast(pe[ct][r]);
    }
  short8 pa = *(const short8*)&Pw[lr * 32 + (((kb ^ (lr & 3)) * 8))];
  __builtin_amdgcn_s_setprio(1);
#pragma unroll
  for (int cc = 0; cc < 8; ++cc) {
    int vrow = cc * 16 + lr;
    short8 vb = *(const short8*)&Vc[vrow * 32 + (((kb ^ (vrow & 3)) * 8))];
    ctx[cc] = __builtin_amdgcn_mfma_f32_16x16x32_bf16(pa, vb, ctx[cc], 0, 0, 0);
  }
  __builtin_amdgcn_s_setprio(0);
}

// grid 1024 x 256thr. Block owns 64 q-rows (x-tile); 4 waves x 16 rows.
// LPT dispatch: xh<16 -> x=31-xh (long first), else x=xh-16 (short backfill).
// 36KB LDS -> 4 blocks/CU co-resident; bh pinned to XCD (T1).
__global__ __launch_bounds__(256) void attn_k(const unsigned short* __restrict__ Q,
                                              const unsigned short* __restrict__ K,
                                              const unsigned short* __restrict__ Vt,
                                              unsigned short* __restrict__ O) {
  __shared__ unsigned short KL[2][32 * 128];
  __shared__ unsigned short VL[2][128 * 32];
  __shared__ unsigned short Pb[4][16 * 32];
  const int t = threadIdx.x, w = t >> 6, l = t & 63;
  const int lr = l & 15, kb = l >> 4;
  const int id = blockIdx.x;
  const int xcd = id & 7, s = id >> 3;          // s: 0..127
  const int bh = xcd * 4 + (s & 3);             // T1: bh pinned to one XCD
  const int xh = s >> 2;                        // 0..31
  const int x = (xh < 16) ? (31 - xh) : (xh - 16);
  const int b = bh >> 4, h = bh & 15;
  const unsigned short* Kh = K + (size_t)b * SEQ * DM + h * NHD;
  const unsigned short* Vh = Vt + (size_t)bh * NHD * SEQ;

  const int qw = x * 64 + w * 16;               // this wave's 16 q-rows
  const int nkt = 2 * x + 2;                    // 32-key tiles

  short8 qf[4];
  {
    const unsigned short* qp = Q + (size_t)(b * SEQ + qw + lr) * DM + h * NHD + kb * 8;
#pragma unroll
    for (int ks = 0; ks < 4; ++ks) qf[ks] = *(const short8*)(qp + ks * 32);
  }
  f32x4 ctx[8] = {};
  float mrow[4], lpart[4];
#pragma unroll
  for (int r = 0; r < 4; ++r) { mrow[r] = -3.0e4f; lpart[r] = 0.f; }

  stage_tiles4(Kh, Vh, KL[0], VL[0], 0, t);
  __syncthreads();

  int cbuf = 0;
#pragma unroll 1
  for (int kt = 0; kt < nkt; ++kt) {
    const int kv0 = kt * 32;
    if (kt + 1 < nkt) stage_tiles4(Kh, Vh, KL[cbuf ^ 1], VL[cbuf ^ 1], kv0 + 32, t);
    if (kv0 <= qw + 15)   // wave-uniform: skip fully-masked diagonal tiles
      attn_tile32(KL[cbuf], VL[cbuf], Pb[w], qf, ctx, mrow, lpart, qw, kv0, lr, kb);
    __syncthreads();
    cbuf ^= 1;
  }

#pragma unroll
  for (int r = 0; r < 4; ++r) {
    float inv = 1.f / red16_sum(lpart[r]);
    size_t rowoff = (size_t)(b * SEQ + qw + kb * 4 + r) * DM + h * NHD;
#pragma unroll
    for (int cc = 0; cc < 8; ++cc)
      O[rowoff + cc * 16 + lr] = f2bf_fast(ctx[cc][r] * inv);
  }
}

// ---------------------------------------------------------------------------
extern "C" void kernel_launch(void* const* d_in, const int* in_sizes, int n_in,
                              void* d_out, int out_size, void* d_ws, size_t ws_size,
                              hipStream_t stream) {
  const float* X  = (const float*)d_in[0];
  const float* Wq = (const float*)d_in[1];
  const float* Wk = (const float*)d_in[2];
  const float* Wv = (const float*)d_in[3];
  const float* Wo = (const float*)d_in[4];
  const float* bo = (const float*)d_in[5];
  float* out = (float*)d_out;

  unsigned short* ws = (unsigned short*)d_ws;
  unsigned short* Xb  = ws;                    // 8388608
  unsigned short* Wqb = ws + 8388608;          // 4194304
  unsigned short* Wkb = ws + 12582912;
  unsigned short* Wvb = ws + 16777216;
  unsigned short* Wob = ws + 20971520;
  unsigned short* Qb  = ws + 25165824;         // 8388608
  unsigned short* Kb  = ws + 33554432;
  unsigned short* Vtb = ws + 41943040;         // Vt[(b*16+h)*128+d][s]
  unsigned short* Cb  = ws + 50331648;

  cast_all_k<<<12288, 256, 0, stream>>>(X, Wq, Wk, Wv, Wo, Xb, Wqb, Wkb, Wvb, Wob);

  gemm_qk_k<<<dim3(8, 16, 2), 512, 0, stream>>>(Xb, Wqb, Wkb, Qb, Kb);
  gemm_vt_k<<<dim3(16, 16), 512, 0, stream>>>(Wvb, Xb, Vtb);
  attn_k<<<1024, 256, 0, stream>>>(Qb, Kb, Vtb, Cb);
  gemm_o_k<<<dim3(8, 32), 512, 0, stream>>>(Cb, Wob, bo, out);
}

// Round 18
// 235.934 us; speedup vs baseline: 1.1415x; 1.1415x over previous
//
#include <hip/hip_runtime.h>

// ---------------------------------------------------------------------------
// MultiHeadAttention: out = softmax_causal((XWq^T)(XWk^T)^T / sqrt(S)) (XWv^T) Wo^T + b
// B=2, S=2048, D=2048, H=16, HD=128.  All compute in bf16 MFMA, fp32 accum.
// Softmax in exp2 domain (Wq pre-scaled by (1/sqrt(S))*log2(e)).
// qk: 256x256 8-phase core; vt/o: 128x256 4-phase core; all XCD-chunked (T1).
// attn: 8-wave 128-row blocks; lazy-max softmax; P via swizzled LDS
// (R11-proven layout); setprio around MFMA clusters (T5).
// [Session ledger: R15 split-K regressed (no occupancy gain, +75% fetch);
//  R17 KVBLK=32 regressed (same waves/CU, 2x per-tile overhead). This R16
//  configuration is the verified optimum of this structure family.]
// ---------------------------------------------------------------------------

typedef __attribute__((ext_vector_type(8))) short short8;
typedef __attribute__((ext_vector_type(4))) float f32x4;

#define SEQ 2048
#define DM  2048
#define NHD 128
#define NT  32    // K-tiles of 64 (GEMM)
#define QSCALE (0.022097086912079608f * 1.4426950408889634f)  // 1/sqrt(2048) * log2(e)

#define EXP2F(x) __builtin_amdgcn_exp2f(x)
#define WAITV(N) asm volatile("s_waitcnt vmcnt(" #N ")" ::: "memory")

__device__ __forceinline__ unsigned short f2bf(float f) {   // RNE
  unsigned u = __builtin_bit_cast(unsigned, f);
  u += 0x7FFFu + ((u >> 16) & 1u);
  return (unsigned short)(u >> 16);
}
__device__ __forceinline__ unsigned short f2bf_fast(float f) {  // round-half-up
  unsigned u = __builtin_bit_cast(unsigned, f);
  return (unsigned short)((u + 0x8000u) >> 16);
}

__device__ __forceinline__ void gll16(const void* g, void* l) {
  __builtin_amdgcn_global_load_lds((const __attribute__((address_space(1))) void*)g,
                                   (__attribute__((address_space(3))) void*)l, 16, 0, 0);
}

// ---- DPP 16-lane reductions (VALU pipe, no LDS crossbar) ------------------
template <int CTRL>
__device__ __forceinline__ float dpp_mv(float x) {
  int xi = __builtin_bit_cast(int, x);
  return __builtin_bit_cast(float,
      __builtin_amdgcn_update_dpp(xi, xi, CTRL, 0xF, 0xF, false));
}
__device__ __forceinline__ float red16_max(float x) {
  x = fmaxf(x, dpp_mv<0xB1>(x));
  x = fmaxf(x, dpp_mv<0x4E>(x));
  x = fmaxf(x, dpp_mv<0x124>(x));
  x = fmaxf(x, dpp_mv<0x128>(x));
  return x;
}
__device__ __forceinline__ float red16_sum(float x) {
  x += dpp_mv<0xB1>(x);
  x += dpp_mv<0x4E>(x);
  x += dpp_mv<0x124>(x);
  x += dpp_mv<0x128>(x);
  return x;
}

// ---------------- fused cast: X + 4 weights in one launch ------------------
__global__ __launch_bounds__(256) void cast_all_k(const float* __restrict__ X,
                                                  const float* __restrict__ Wq,
                                                  const float* __restrict__ Wk,
                                                  const float* __restrict__ Wv,
                                                  const float* __restrict__ Wo,
                                                  unsigned short* __restrict__ Xb,
                                                  unsigned short* __restrict__ Wqb,
                                                  unsigned short* __restrict__ Wkb,
                                                  unsigned short* __restrict__ Wvb,
                                                  unsigned short* __restrict__ Wob) {
  int i = blockIdx.x * 256 + threadIdx.x;
  const float* src;
  unsigned short* dst;
  int j;
  float sc = 1.0f;
  if (i < 1048576) {
    src = X; dst = Xb; j = i;
  } else {
    int k = i - 1048576;
    int r = k >> 19; j = k & 524287;
    src = (r == 0) ? Wq : (r == 1) ? Wk : (r == 2) ? Wv : Wo;
    dst = (r == 0) ? Wqb : (r == 1) ? Wkb : (r == 2) ? Wvb : Wob;
    if (r == 0) sc = QSCALE;
  }
  const f32x4* p = (const f32x4*)src + (size_t)j * 2;
  f32x4 a = p[0], b = p[1];
  short8 o;
  o[0] = (short)f2bf(a[0] * sc); o[1] = (short)f2bf(a[1] * sc);
  o[2] = (short)f2bf(a[2] * sc); o[3] = (short)f2bf(a[3] * sc);
  o[4] = (short)f2bf(b[0] * sc); o[5] = (short)f2bf(b[1] * sc);
  o[6] = (short)f2bf(b[2] * sc); o[7] = (short)f2bf(b[3] * sc);
  *(short8*)(dst + (size_t)j * 8) = o;
}

// ---------------- shared staging helper (GEMM) -----------------------------
__device__ __forceinline__ void stage_half(const unsigned short* __restrict__ gbase,
                                           unsigned short* lhalf, int tid) {
#pragma unroll
  for (int c = 0; c < 2; ++c) {
    int G = c * 512 + tid;
    int row = G >> 3, g = G & 7;
    int gs = g ^ (row & 7);
    gll16(gbase + (size_t)row * DM + gs * 8, lhalf + (size_t)G * 8);
  }
}

// ---------------- 256x256 8-phase core (qk) --------------------------------
#define LOADAF(MH)                                                              \
  _Pragma("unroll") for (int mi = 0; mi < 4; ++mi)                              \
    _Pragma("unroll") for (int ks = 0; ks < 2; ++ks) {                          \
      int row = wm * 64 + mi * 16 + lr;                                         \
      af[mi][ks] = *(const short8*)&lA[(MH) * 8192 + row * 64 +                 \
                                       (((ks * 4 + kb) ^ (row & 7)) * 8)];      \
    }

#define PHASE(MH, NH, STG, WV)                                                  \
  {                                                                             \
    const unsigned short* lBh = lB + (NH) * 8192;                               \
    short8 bfr[2][2];                                                           \
    _Pragma("unroll") for (int ni = 0; ni < 2; ++ni)                            \
      _Pragma("unroll") for (int ks = 0; ks < 2; ++ks) {                        \
        int row = wn * 32 + ni * 16 + lr;                                       \
        bfr[ni][ks] = *(const short8*)&lBh[row * 64 + (((ks * 4 + kb) ^ (row & 7)) * 8)]; \
      }                                                                         \
    STG;                                                                        \
    __builtin_amdgcn_s_barrier();                                               \
    __builtin_amdgcn_s_setprio(1);                                              \
    _Pragma("unroll") for (int mi = 0; mi < 4; ++mi)                            \
      _Pragma("unroll") for (int ni = 0; ni < 2; ++ni) {                        \
        acc[MH][NH][mi][ni] = __builtin_amdgcn_mfma_f32_16x16x32_bf16(          \
            af[mi][0], bfr[ni][0], acc[MH][NH][mi][ni], 0, 0, 0);               \
        acc[MH][NH][mi][ni] = __builtin_amdgcn_mfma_f32_16x16x32_bf16(          \
            af[mi][1], bfr[ni][1], acc[MH][NH][mi][ni], 0, 0, 0);               \
      }                                                                         \
    __builtin_amdgcn_s_setprio(0);                                              \
    WV;                                                                         \
    __builtin_amdgcn_s_barrier();                                               \
  }

__device__ __forceinline__ void gemm256_core(const unsigned short* __restrict__ A,
                                             const unsigned short* __restrict__ B,
                                             unsigned short* LA, unsigned short* LB,
                                             f32x4 acc[2][2][4][2], int m0, int n0) {
  const int tid = threadIdx.x;
  const int w = tid >> 6, l = tid & 63;
  const int lr = l & 15, kb = l >> 4;
  const int wm = w >> 2, wn = w & 3;

  stage_half(A + (size_t)m0 * DM, LA, tid);
  stage_half(B + (size_t)n0 * DM, LB, tid);
  stage_half(B + (size_t)n0 * DM + (size_t)128 * DM, LB + 8192, tid);
  stage_half(A + (size_t)m0 * DM + (size_t)128 * DM, LA + 8192, tid);
  WAITV(4);
  __builtin_amdgcn_s_barrier();

#pragma unroll 1
  for (int t = 0; t < NT; ++t) {
    const unsigned short* lA = LA + (t & 1) * 16384;
    const unsigned short* lB = LB + (t & 1) * 16384;
    unsigned short* sA = LA + ((t + 1) & 1) * 16384;
    unsigned short* sB = LB + ((t + 1) & 1) * 16384;
    const unsigned short* gA = A + (size_t)m0 * DM + (t + 1) * 64;
    const unsigned short* gB = B + (size_t)n0 * DM + (t + 1) * 64;
    const bool st = (t + 1 < NT);
    short8 af[4][2];
    LOADAF(0);
    PHASE(0, 0, if (st) stage_half(gA, sA, tid),
                if (st) { WAITV(4); } else { WAITV(2); });
    PHASE(0, 1, if (st) stage_half(gB, sB, tid),
                if (st) { WAITV(4); } else { WAITV(0); });
    LOADAF(1);
    PHASE(1, 0, if (st) stage_half(gB + (size_t)128 * DM, sB + 8192, tid), );
    PHASE(1, 1, if (st) stage_half(gA + (size_t)128 * DM, sA + 8192, tid),
                if (st) { WAITV(4); });
  }
}

// Q and K projections. Grid (8,16,2). XCD-chunk remap: per XCD 4y x 4x x 2z.
__global__ __launch_bounds__(512, 2) void gemm_qk_k(const unsigned short* __restrict__ X,
                                                    const unsigned short* __restrict__ Wq,
                                                    const unsigned short* __restrict__ Wk,
                                                    unsigned short* __restrict__ Qo,
                                                    unsigned short* __restrict__ Ko) {
  __shared__ unsigned short LA[32768];
  __shared__ unsigned short LB[32768];
  const int lin = blockIdx.x + 8 * (blockIdx.y + 16 * blockIdx.z);
  const int c = lin & 7, idx = lin >> 3;
  const int xb = (c & 1) * 4 + ((idx >> 2) & 3);
  const int yb = (c >> 1) * 4 + (idx & 3);
  const int zb = idx >> 4;
  const unsigned short* W = zb ? Wk : Wq;
  unsigned short* Y = zb ? Ko : Qo;
  const int m0 = yb * 256, n0 = xb * 256;
  const int tid = threadIdx.x, w = tid >> 6, l = tid & 63;
  const int lr = l & 15, kb = l >> 4;
  const int wm = w >> 2, wn = w & 3;
  f32x4 acc[2][2][4][2] = {};
  gemm256_core(X, W, LA, LB, acc, m0, n0);
#pragma unroll
  for (int mh = 0; mh < 2; ++mh)
#pragma unroll
    for (int nh = 0; nh < 2; ++nh)
#pragma unroll
      for (int mi = 0; mi < 4; ++mi)
#pragma unroll
        for (int ni = 0; ni < 2; ++ni)
#pragma unroll
          for (int rr = 0; rr < 4; ++rr) {
            int row = m0 + mh * 128 + wm * 64 + mi * 16 + kb * 4 + rr;
            int col = n0 + nh * 128 + wn * 32 + ni * 16 + lr;
            Y[(size_t)row * DM + col] = f2bf(acc[mh][nh][mi][ni][rr]);
          }
}

// ---------------- 128x256 4-phase core (vt, o) -----------------------------
#define PH2(NH, STG, WV)                                                        \
  {                                                                             \
    const unsigned short* lBh = lB + (NH) * 8192;                               \
    short8 bfr[2][2];                                                           \
    _Pragma("unroll") for (int ni = 0; ni < 2; ++ni)                            \
      _Pragma("unroll") for (int ks = 0; ks < 2; ++ks) {                        \
        int row = wn * 32 + ni * 16 + lr;                                       \
        bfr[ni][ks] = *(const short8*)&lBh[row * 64 + (((ks * 4 + kb) ^ (row & 7)) * 8)]; \
      }                                                                         \
    STG;                                                                        \
    __builtin_amdgcn_s_barrier();                                               \
    __builtin_amdgcn_s_setprio(1);                                              \
    _Pragma("unroll") for (int mi = 0; mi < 4; ++mi)                            \
      _Pragma("unroll") for (int ni = 0; ni < 2; ++ni) {                        \
        acc[NH][mi][ni] = __builtin_amdgcn_mfma_f32_16x16x32_bf16(              \
            af[mi][0], bfr[ni][0], acc[NH][mi][ni], 0, 0, 0);                   \
        acc[NH][mi][ni] = __builtin_amdgcn_mfma_f32_16x16x32_bf16(              \
            af[mi][1], bfr[ni][1], acc[NH][mi][ni], 0, 0, 0);                   \
      }                                                                         \
    __builtin_amdgcn_s_setprio(0);                                              \
    WV;                                                                         \
    __builtin_amdgcn_s_barrier();                                               \
  }

__device__ __forceinline__ void gemm128x256_core(const unsigned short* __restrict__ A,
                                                 const unsigned short* __restrict__ B,
                                                 unsigned short* LA, unsigned short* LB,
                                                 f32x4 acc[2][4][2], int m0, int n0) {
  const int tid = threadIdx.x;
  const int w = tid >> 6, l = tid & 63;
  const int lr = l & 15, kb = l >> 4;
  const int wm = w >> 2, wn = w & 3;

  stage_half(A + (size_t)m0 * DM, LA, tid);
  stage_half(B + (size_t)n0 * DM, LB, tid);
  stage_half(B + (size_t)n0 * DM + (size_t)128 * DM, LB + 8192, tid);
  WAITV(2);
  __builtin_amdgcn_s_barrier();

#pragma unroll 1
  for (int t = 0; t < NT; ++t) {
    const unsigned short* lA = LA + (t & 1) * 8192;
    const unsigned short* lB = LB + (t & 1) * 16384;
    unsigned short* sA = LA + ((t + 1) & 1) * 8192;
    unsigned short* sB = LB + ((t + 1) & 1) * 16384;
    const unsigned short* gA = A + (size_t)m0 * DM + (t + 1) * 64;
    const unsigned short* gB = B + (size_t)n0 * DM + (t + 1) * 64;
    const bool st = (t + 1 < NT);
    short8 af[4][2];
#pragma unroll
    for (int mi = 0; mi < 4; ++mi)
#pragma unroll
      for (int ks = 0; ks < 2; ++ks) {
        int row = wm * 64 + mi * 16 + lr;
        af[mi][ks] = *(const short8*)&lA[row * 64 + (((ks * 4 + kb) ^ (row & 7)) * 8)];
      }
    PH2(0, if (st) stage_half(gA, sA, tid),
           if (st) { WAITV(2); } else { WAITV(0); });
    PH2(1, if (st) { stage_half(gB, sB, tid); stage_half(gB + (size_t)128 * DM, sB + 8192, tid); },
           if (st) { WAITV(2); });
  }
}

__global__ __launch_bounds__(512, 2) void gemm_vt_k(const unsigned short* __restrict__ Wv,
                                                    const unsigned short* __restrict__ X,
                                                    unsigned short* __restrict__ Vt) {
  __shared__ unsigned short LA[16384];
  __shared__ unsigned short LB[32768];
  const int lin = blockIdx.x + 16 * blockIdx.y;
  const int c = lin & 7, idx = lin >> 3;
  const int yb = (c >> 2) * 8 + (idx & 7);
  const int xb = (c & 3) * 4 + (idx >> 3);
  const int m0 = yb * 128, n0 = xb * 256;
  const int tid = threadIdx.x, w = tid >> 6, l = tid & 63;
  const int lr = l & 15, kb = l >> 4;
  const int wm = w >> 2, wn = w & 3;
  f32x4 acc[2][4][2] = {};
  gemm128x256_core(Wv, X, LA, LB, acc, m0, n0);
#pragma unroll
  for (int nh = 0; nh < 2; ++nh)
#pragma unroll
    for (int mi = 0; mi < 4; ++mi)
#pragma unroll
      for (int ni = 0; ni < 2; ++ni)
#pragma unroll
        for (int rr = 0; rr < 4; ++rr) {
          int i = m0 + wm * 64 + mi * 16 + kb * 4 + rr;             // h*128+d
          int j = n0 + nh * 128 + wn * 32 + ni * 16 + lr;           // b*2048+s
          Vt[((size_t)(j >> 11) * 2048 + i) * 2048 + (j & 2047)] = f2bf(acc[nh][mi][ni][rr]);
        }
}

__global__ __launch_bounds__(512, 2) void gemm_o_k(const unsigned short* __restrict__ A,
                                                   const unsigned short* __restrict__ W,
                                                   const float* __restrict__ bias,
                                                   float* __restrict__ Y) {
  __shared__ unsigned short LA[16384];
  __shared__ unsigned short LB[32768];
  const int lin = blockIdx.x + 8 * blockIdx.y;
  const int c = lin & 7, idx = lin >> 3;
  const int yb = (c >> 1) * 8 + (idx & 7);
  const int xb = (c & 1) * 4 + (idx >> 3);
  const int m0 = yb * 128, n0 = xb * 256;
  const int tid = threadIdx.x, w = tid >> 6, l = tid & 63;
  const int lr = l & 15, kb = l >> 4;
  const int wm = w >> 2, wn = w & 3;
  f32x4 acc[2][4][2] = {};
  gemm128x256_core(A, W, LA, LB, acc, m0, n0);
#pragma unroll
  for (int nh = 0; nh < 2; ++nh)
#pragma unroll
    for (int mi = 0; mi < 4; ++mi)
#pragma unroll
      for (int ni = 0; ni < 2; ++ni)
#pragma unroll
        for (int rr = 0; rr < 4; ++rr) {
          int row = m0 + wm * 64 + mi * 16 + kb * 4 + rr;
          int col = n0 + nh * 128 + wn * 32 + ni * 16 + lr;
          Y[(size_t)row * DM + col] = acc[nh][mi][ni][rr] + bias[col];
        }
}

// ---------------- flash attention, causal, exp2-domain softmax -------------
__device__ __forceinline__ void stage_tiles8(const unsigned short* __restrict__ Kh,
                                             const unsigned short* __restrict__ Vh,
                                             unsigned short* KL, unsigned short* VL,
                                             int kv0, int t) {
#pragma unroll
  for (int c = 0; c < 2; ++c) {          // K: slot S = row*16 + (g^(row&7))
    int S = c * 512 + t;
    int row = S >> 4, g = (S & 15) ^ (row & 7);
    gll16(Kh + (size_t)(kv0 + row) * DM + g * 8, KL + (size_t)S * 8);
  }
#pragma unroll
  for (int c = 0; c < 2; ++c) {          // V: slot S = d*8 + (g^(d&7))
    int S = c * 512 + t;
    int d = S >> 3, g = (S & 7) ^ (d & 7);
    gll16(Vh + (size_t)d * SEQ + kv0 + g * 8, VL + (size_t)S * 8);
  }
}

// One 64-key tile for one 16-row q-group. Lazy-max softmax; P via the
// R11-proven swizzled LDS path; setprio (T5) around both MFMA clusters.
__device__ __forceinline__ void attn_tile(const unsigned short* __restrict__ Kc,
                                          const unsigned short* __restrict__ Vc,
                                          unsigned short* __restrict__ Pw,
                                          const short8 qf[4], f32x4 ctx[8],
                                          float mrow[4], float lpart[4],
                                          int qw, int kv0, int lr, int kb) {
  f32x4 s[4];
  __builtin_amdgcn_s_setprio(1);
#pragma unroll
  for (int ct = 0; ct < 4; ++ct) {
    s[ct] = (f32x4){0.f, 0.f, 0.f, 0.f};
    int krow = ct * 16 + lr;
#pragma unroll
    for (int ks = 0; ks < 4; ++ks) {
      short8 bf = *(const short8*)&Kc[krow * 128 + (((ks * 4 + kb) ^ (krow & 7)) * 8)];
      s[ct] = __builtin_amdgcn_mfma_f32_16x16x32_bf16(qf[ks], bf, s[ct], 0, 0, 0);
    }
  }
  __builtin_amdgcn_s_setprio(0);
  if (kv0 + 63 > qw) {                  // diagonal tile: causal mask
#pragma unroll
    for (int r = 0; r < 4; ++r) {
      const int qi = qw + kb * 4 + r;
#pragma unroll
      for (int ct = 0; ct < 4; ++ct)
        if (kv0 + ct * 16 + lr > qi) s[ct][r] = -3.0e4f;
    }
  }
  float mxl[4];
#pragma unroll
  for (int r = 0; r < 4; ++r)
    mxl[r] = fmaxf(fmaxf(s[0][r], s[1][r]), fmaxf(s[2][r], s[3][r]));
  bool hit = (mxl[0] > mrow[0] + 8.f) | (mxl[1] > mrow[1] + 8.f) |
             (mxl[2] > mrow[2] + 8.f) | (mxl[3] > mrow[3] + 8.f);
  if (__any(hit)) {                     // rare after first tile
#pragma unroll
    for (int r = 0; r < 4; ++r) {
      float mx = red16_max(mxl[r]);
      if (mx > mrow[r] + 8.f) {
        float alpha = EXP2F(mrow[r] - mx);
        mrow[r] = mx;
        lpart[r] *= alpha;
#pragma unroll
        for (int cc = 0; cc < 8; ++cc) ctx[cc][r] *= alpha;
      }
    }
  }
  float pe[4][4];
#pragma unroll
  for (int r = 0; r < 4; ++r) {
#pragma unroll
    for (int ct = 0; ct < 4; ++ct) {
      float e = EXP2F(s[ct][r] - mrow[r]);
      pe[ct][r] = e;
      lpart[r] += e;
    }
  }
  // P -> per-wave LDS (conflict-spread swizzle, R11-proven)
#pragma unroll
  for (int ct = 0; ct < 4; ++ct)
#pragma unroll
    for (int r = 0; r < 4; ++r) {
      int prow = kb * 4 + r;
      int g = (ct * 2 + (lr >> 3)) ^ ((prow >> 1) & 7);
      Pw[prow * 64 + g * 8 + (lr & 7)] = f2bf_fast(pe[ct][r]);
    }
  short8 pa[2];
#pragma unroll
  for (int ks = 0; ks < 2; ++ks)
    pa[ks] = *(const short8*)&Pw[lr * 64 + (((ks * 4 + kb) ^ ((lr >> 1) & 7)) * 8)];
  __builtin_amdgcn_s_setprio(1);
#pragma unroll
  for (int cc = 0; cc < 8; ++cc) {
    int vrow = cc * 16 + lr;
#pragma unroll
    for (int ks = 0; ks < 2; ++ks) {
      short8 vb = *(const short8*)&Vc[vrow * 64 + (((ks * 4 + kb) ^ (vrow & 7)) * 8)];
      ctx[cc] = __builtin_amdgcn_mfma_f32_16x16x32_bf16(pa[ks], vb, ctx[cc], 0, 0, 0);
    }
  }
  __builtin_amdgcn_s_setprio(0);
}

// grid 512 x 512thr. Block owns 128 q-rows; 8 waves x 16 rows. Balanced
// y/15-y dispatch; bh pinned to XCD (T1).
__global__ __launch_bounds__(512) void attn_k(const unsigned short* __restrict__ Q,
                                              const unsigned short* __restrict__ K,
                                              const unsigned short* __restrict__ Vt,
                                              unsigned short* __restrict__ O) {
  __shared__ unsigned short KL[2][64 * 128];
  __shared__ unsigned short VL[2][128 * 64];
  __shared__ unsigned short Pb[8][16 * 64];
  const int t = threadIdx.x, w = t >> 6, l = t & 63;
  const int lr = l & 15, kb = l >> 4;
  const int id = blockIdx.x;
  const int xcd = id & 7, s = id >> 3;
  const int bh = xcd * 4 + (s & 3);
  const int yh = s >> 2;
  const int y = (yh < 8) ? yh : (23 - yh);
  const int b = bh >> 4, h = bh & 15;
  const unsigned short* Kh = K + (size_t)b * SEQ * DM + h * NHD;
  const unsigned short* Vh = Vt + (size_t)bh * NHD * SEQ;

  const int qw = y * 128 + w * 16;
  const int nkt = 2 * y + 2;

  short8 qf[4];
  {
    const unsigned short* qp = Q + (size_t)(b * SEQ + qw + lr) * DM + h * NHD + kb * 8;
#pragma unroll
    for (int ks = 0; ks < 4; ++ks) qf[ks] = *(const short8*)(qp + ks * 32);
  }
  f32x4 ctx[8] = {};
  float mrow[4], lpart[4];
#pragma unroll
  for (int r = 0; r < 4; ++r) { mrow[r] = -3.0e4f; lpart[r] = 0.f; }

  stage_tiles8(Kh, Vh, KL[0], VL[0], 0, t);
  __syncthreads();

  int cbuf = 0;
#pragma unroll 1
  for (int kt = 0; kt < nkt; ++kt) {
    const int kv0 = kt * 64;
    if (kt + 1 < nkt) stage_tiles8(Kh, Vh, KL[cbuf ^ 1], VL[cbuf ^ 1], kv0 + 64, t);
    if (kv0 <= qw + 15)   // wave-uniform: skip fully-masked diagonal tiles
      attn_tile(KL[cbuf], VL[cbuf], Pb[w], qf, ctx, mrow, lpart, qw, kv0, lr, kb);
    __syncthreads();
    cbuf ^= 1;
  }

#pragma unroll
  for (int r = 0; r < 4; ++r) {
    float inv = 1.f / red16_sum(lpart[r]);
    size_t rowoff = (size_t)(b * SEQ + qw + kb * 4 + r) * DM + h * NHD;
#pragma unroll
    for (int cc = 0; cc < 8; ++cc)
      O[rowoff + cc * 16 + lr] = f2bf_fast(ctx[cc][r] * inv);
  }
}

// ---------------------------------------------------------------------------
extern "C" void kernel_launch(void* const* d_in, const int* in_sizes, int n_in,
                              void* d_out, int out_size, void* d_ws, size_t ws_size,
                              hipStream_t stream) {
  const float* X  = (const float*)d_in[0];
  const float* Wq = (const float*)d_in[1];
  const float* Wk = (const float*)d_in[2];
  const float* Wv = (const float*)d_in[3];
  const float* Wo = (const float*)d_in[4];
  const float* bo = (const float*)d_in[5];
  float* out = (float*)d_out;

  unsigned short* ws = (unsigned short*)d_ws;
  unsigned short* Xb  = ws;                    // 8388608
  unsigned short* Wqb = ws + 8388608;          // 4194304
  unsigned short* Wkb = ws + 12582912;
  unsigned short* Wvb = ws + 16777216;
  unsigned short* Wob = ws + 20971520;
  unsigned short* Qb  = ws + 25165824;         // 8388608
  unsigned short* Kb  = ws + 33554432;
  unsigned short* Vtb = ws + 41943040;         // Vt[(b*16+h)*128+d][s]
  unsigned short* Cb  = ws + 50331648;

  cast_all_k<<<12288, 256, 0, stream>>>(X, Wq, Wk, Wv, Wo, Xb, Wqb, Wkb, Wvb, Wob);

  gemm_qk_k<<<dim3(8, 16, 2), 512, 0, stream>>>(Xb, Wqb, Wkb, Qb, Kb);
  gemm_vt_k<<<dim3(16, 16), 512, 0, stream>>>(Wvb, Xb, Vtb);
  attn_k<<<512, 512, 0, stream>>>(Qb, Kb, Vtb, Cb);
  gemm_o_k<<<dim3(8, 32), 512, 0, stream>>>(Cb, Wob, bo, out);
}